// Round 9
// baseline (988.045 us; speedup 1.0000x reference)
//
#include <hip/hip_runtime.h>
#include <hip/hip_bf16.h>

#define NN 32
#define LL 4096
#define EE 512
#define HH 8
#define DD 64
#define FF 2048
#define CC 8            // fallback path: row chunks per head-block

typedef float f32x4 __attribute__((ext_vector_type(4)));

#define GRIDN 1024
#define CNT_OFF 700000   // float offset of barrier counters inside ws

// ---------------------------------------------------------------------------
// Grid barrier with DEVICE-SCOPE coherent spin.
// R8 lesson: a relaxed plain load spins on the stale XCD-local L2 copy
// (per-XCD L2s are not coherent) and only resolves via accidental eviction
// (~120 us/barrier). Agent-scope atomic load bypasses L2 -> fresh value.
__device__ __forceinline__ void gridbar(unsigned* cnt) {
    __syncthreads();
    if (threadIdx.x == 0) {
        __threadfence();   // release: write back dirty L2 (agent scope)
        __hip_atomic_fetch_add(cnt, 1u, __ATOMIC_RELEASE,
                               __HIP_MEMORY_SCOPE_AGENT);
        while (__hip_atomic_load(cnt, __ATOMIC_ACQUIRE,
                                 __HIP_MEMORY_SCOPE_AGENT) < (unsigned)GRIDN)
            __builtin_amdgcn_s_sleep(2);
        __threadfence();   // acquire: invalidate stale caches
    }
    __syncthreads();
}

// ===========================================================================
// PATH 1: single cooperative kernel, hand-rolled coherent barriers.
// ===========================================================================
__global__ __launch_bounds__(256, 4) void k_mega(
    const float* __restrict__ Cp, const float* __restrict__ W1,
    const float* __restrict__ W3, const float* __restrict__ Wf1,
    const float* __restrict__ bf1, const float* __restrict__ Wf2,
    const float* __restrict__ bf2, const float* __restrict__ gamma,
    const float* __restrict__ beta, float* __restrict__ out,
    float* __restrict__ ws)
{
    __shared__ float lds[EE + 256];     // 3 KB

    float* P   = ws;                    // 4*32*8*512 = 524288 floats
    float* V   = P + 524288;
    float* phi = V + DD * EE;
    float* w3  = phi + NN * EE;
    float* h1  = w3 + NN * EE;
    float* x   = h1 + NN * FF;
    unsigned* cnt = (unsigned*)(ws + CNT_OFF);

    const int b    = blockIdx.x;
    const int t    = threadIdx.x;
    const int lane = t & 63;
    const int wwid = (b << 2) | (t >> 6);

    // Phase A: Cp 128-row partial sums; every block also does 8 V-outputs.
    {
        int n    = b >> 5;
        int sub  = b & 31;
        int h    = sub >> 2;
        int q    = sub & 3;
        int e4   = t & 127;
        int half = t >> 7;
        const f32x4* base = reinterpret_cast<const f32x4*>(Cp) +
            (size_t)(n * LL + sub * 128 + half) * (EE / 4) + e4;
        float ax = 0.f, ay = 0.f, az = 0.f, aw = 0.f;
#pragma unroll 8
        for (int r = 0; r < 64; ++r) {
            f32x4 v = base[(size_t)r * 2 * (EE / 4)];
            ax += v.x; ay += v.y; az += v.z; aw += v.w;
        }
        f32x4* sh = reinterpret_cast<f32x4*>(lds);
        if (half) { f32x4 o; o.x = ax; o.y = ay; o.z = az; o.w = aw; sh[e4] = o; }
        __syncthreads();
        if (!half) {
            f32x4 o = sh[e4];
            o.x += ax; o.y += ay; o.z += az; o.w += aw;
            reinterpret_cast<f32x4*>(P)[(size_t)((q * NN + n) * HH + h) * 128 + e4] = o;
        }
        if (t < 8) {
            int idx = b * 8 + t;
            int d = idx >> 7, ee4 = idx & 127;
            f32x4 a = reinterpret_cast<const f32x4*>(W1)[(size_t)d * 128 + ee4];
#pragma unroll
            for (int j = 1; j < 8; ++j) {
                f32x4 v = reinterpret_cast<const f32x4*>(
                    W1 + (size_t)(j * 64 + d) * EE)[ee4];
                a.x += v.x; a.y += v.y; a.z += v.z; a.w += v.w;
            }
            reinterpret_cast<f32x4*>(V)[(size_t)d * 128 + ee4] = a;
        }
    }
    gridbar(cnt + 0);

    // Phase B: phi (blocks 0..255), coalesced-V wave-per-d
    if (b < 256) {
        int n = b >> 3, h = b & 7;
        float* S = lds;
#pragma unroll
        for (int rep = 0; rep < 2; ++rep) {
            int e = t + rep * 256;
            float s = 0.f;
#pragma unroll
            for (int q = 0; q < 4; ++q)
                s += P[(size_t)((q * NN + n) * HH + h) * EE + e];
            S[e] = s;
        }
        __syncthreads();
        int w = t >> 6;
        const f32x4* S4 = reinterpret_cast<const f32x4*>(S);
        f32x4 s0 = S4[lane];
        f32x4 s1 = S4[64 + lane];
#pragma unroll
        for (int i = 0; i < 16; ++i) {
            int d = w * 16 + i;
            const f32x4* Vr = reinterpret_cast<const f32x4*>(V) + (size_t)d * 128;
            f32x4 v0 = Vr[lane];
            f32x4 v1 = Vr[64 + lane];
            float acc = s0.x * v0.x + s0.y * v0.y + s0.z * v0.z + s0.w * v0.w
                      + s1.x * v1.x + s1.y * v1.y + s1.z * v1.z + s1.w * v1.w;
#pragma unroll
            for (int m = 32; m > 0; m >>= 1) acc += __shfl_xor(acc, m);
            if (lane == 0) phi[(size_t)n * EE + h * DD + d] = acc;
        }
    }
    gridbar(cnt + 1);

    // Phase C: w3 = phi @ W3^T   (4096 waves: f=wwid>>3, 8 n-groups of 4)
    {
        int f = wwid >> 3, ng = wwid & 7, n0 = ng * 4;
        float acc[4] = {0.f, 0.f, 0.f, 0.f};
#pragma unroll
        for (int k = 0; k < 2; ++k) {
            f32x4 w4 = reinterpret_cast<const f32x4*>(W3 + (size_t)f * EE)[k * 64 + lane];
#pragma unroll
            for (int g = 0; g < 4; ++g) {
                f32x4 a4 = reinterpret_cast<const f32x4*>(
                    phi + (size_t)(n0 + g) * EE)[k * 64 + lane];
                acc[g] += a4.x * w4.x + a4.y * w4.y + a4.z * w4.z + a4.w * w4.w;
            }
        }
#pragma unroll
        for (int g = 0; g < 4; ++g) {
            float s = acc[g];
#pragma unroll
            for (int m = 32; m; m >>= 1) s += __shfl_xor(s, m);
            if (lane == 0) w3[(size_t)(n0 + g) * EE + f] = s;
        }
    }
    gridbar(cnt + 2);

    // Phase D: h1 = relu(w3 @ Wf1^T + bf1)  (4096 waves: 2 f, 4 n-groups of 8)
    {
        int f0 = (wwid >> 2) * 2, ng = wwid & 3, n0 = ng * 8;
        float acc[8][2] = {};
#pragma unroll
        for (int fi = 0; fi < 2; ++fi) {
#pragma unroll
            for (int k = 0; k < 2; ++k) {
                f32x4 w4 = reinterpret_cast<const f32x4*>(
                    Wf1 + (size_t)(f0 + fi) * EE)[k * 64 + lane];
#pragma unroll
                for (int g = 0; g < 8; ++g) {
                    f32x4 a4 = reinterpret_cast<const f32x4*>(
                        w3 + (size_t)(n0 + g) * EE)[k * 64 + lane];
                    acc[g][fi] += a4.x * w4.x + a4.y * w4.y + a4.z * w4.z + a4.w * w4.w;
                }
            }
        }
#pragma unroll
        for (int fi = 0; fi < 2; ++fi) {
#pragma unroll
            for (int g = 0; g < 8; ++g) {
                float s = acc[g][fi];
#pragma unroll
                for (int m = 32; m; m >>= 1) s += __shfl_xor(s, m);
                if (lane == 0)
                    h1[(size_t)(n0 + g) * FF + f0 + fi] = fmaxf(s + bf1[f0 + fi], 0.f);
            }
        }
    }
    gridbar(cnt + 3);

    // Phase E: x = h1 @ Wf2^T + bf2 + w3  (4096 waves)
    {
        int f = wwid >> 3, ng = wwid & 7, n0 = ng * 4;
        float acc[4] = {0.f, 0.f, 0.f, 0.f};
#pragma unroll
        for (int k = 0; k < 8; ++k) {
            f32x4 w4 = reinterpret_cast<const f32x4*>(Wf2 + (size_t)f * FF)[k * 64 + lane];
#pragma unroll
            for (int g = 0; g < 4; ++g) {
                f32x4 a4 = reinterpret_cast<const f32x4*>(
                    h1 + (size_t)(n0 + g) * FF)[k * 64 + lane];
                acc[g] += a4.x * w4.x + a4.y * w4.y + a4.z * w4.z + a4.w * w4.w;
            }
        }
#pragma unroll
        for (int g = 0; g < 4; ++g) {
            float s = acc[g];
#pragma unroll
            for (int m = 32; m; m >>= 1) s += __shfl_xor(s, m);
            if (lane == 0)
                x[(size_t)(n0 + g) * EE + f] =
                    s + bf2[f] + w3[(size_t)(n0 + g) * EE + f];
        }
    }
    gridbar(cnt + 4);

    // Phase F: LayerNorm (blocks 0..31)
    if (b < NN) {
        float* wred = lds;
        int n = b;
        float a0 = x[(size_t)n * EE + t];
        float b0 = x[(size_t)n * EE + 256 + t];
        float s = a0 + b0;
#pragma unroll
        for (int off = 32; off > 0; off >>= 1) s += __shfl_down(s, off);
        int wid = t >> 6;
        if ((t & 63) == 0) wred[wid] = s;
        __syncthreads();
        if (t == 0) wred[0] = (wred[0] + wred[1] + wred[2] + wred[3]) * (1.0f / EE);
        __syncthreads();
        float mu = wred[0];
        float da = a0 - mu, db = b0 - mu;
        float q = da * da + db * db;
#pragma unroll
        for (int off = 32; off > 0; off >>= 1) q += __shfl_down(q, off);
        __syncthreads();
        if ((t & 63) == 0) wred[wid] = q;
        __syncthreads();
        if (t == 0) wred[0] = (wred[0] + wred[1] + wred[2] + wred[3]) * (1.0f / EE);
        __syncthreads();
        float var = wred[0];
        float rstd = rsqrtf(var + 1e-5f);
        out[(size_t)n * EE + t]       = da * rstd * gamma[t] + beta[t];
        out[(size_t)n * EE + 256 + t] = db * rstd * gamma[t + 256] + beta[t + 256];
    }
}

// ===========================================================================
// PATH 2 (fallback): the verified R7 six-kernel pipeline.
// ===========================================================================
__global__ void k_prep(const float* __restrict__ Cp, const float* __restrict__ W1,
                       float* __restrict__ P, float* __restrict__ V) {
    int bid = blockIdx.x;
    int tid = threadIdx.x;
    if (bid < 2048) {
        int c = bid & 7;
        int h = (bid >> 3) & 7;
        int n = bid >> 6;
        const float4* base = reinterpret_cast<const float4*>(
            Cp + ((size_t)n * LL + (size_t)h * 512 + (size_t)c * 64) * EE) + tid;
        float ax = 0.f, ay = 0.f, az = 0.f, aw = 0.f;
#pragma unroll 8
        for (int r = 0; r < 64; ++r) {
            float4 v = base[(size_t)r * (EE / 4)];
            ax += v.x; ay += v.y; az += v.z; aw += v.w;
        }
        float4 o; o.x = ax; o.y = ay; o.z = az; o.w = aw;
        reinterpret_cast<float4*>(P + (((size_t)c * NN + n) * HH + h) * EE)[tid] = o;
    } else {
        int gid2 = (bid - 2048) * 128 + tid;
#pragma unroll
        for (int rep = 0; rep < 2; ++rep) {
            int idx = gid2 + rep * 4096;
            int d = idx >> 7;
            int e4 = idx & 127;
            float ax = 0.f, ay = 0.f, az = 0.f, aw = 0.f;
#pragma unroll
            for (int j = 0; j < 8; ++j) {
                float4 v = reinterpret_cast<const float4*>(
                    W1 + (size_t)(j * 64 + d) * EE)[e4];
                ax += v.x; ay += v.y; az += v.z; aw += v.w;
            }
            float4 o; o.x = ax; o.y = ay; o.z = az; o.w = aw;
            reinterpret_cast<float4*>(V + (size_t)d * EE)[e4] = o;
        }
    }
}

__global__ __launch_bounds__(256) void k_phi(const float* __restrict__ P,
                                             const float* __restrict__ V,
                                             float* __restrict__ phi) {
    __shared__ float S[EE];
    int n = blockIdx.x >> 3;
    int h = blockIdx.x & 7;
    int t = threadIdx.x;
#pragma unroll
    for (int rep = 0; rep < 2; ++rep) {
        int e = t + rep * 256;
        float s = 0.f;
#pragma unroll
        for (int c = 0; c < CC; ++c)
            s += P[(((size_t)c * NN + n) * HH + h) * EE + e];
        S[e] = s;
    }
    __syncthreads();
    int w    = t >> 6;
    int lane = t & 63;
    const f32x4* S4 = reinterpret_cast<const f32x4*>(S);
    f32x4 s0 = S4[lane];
    f32x4 s1 = S4[64 + lane];
#pragma unroll
    for (int i = 0; i < 16; ++i) {
        int d = w * 16 + i;
        const f32x4* Vr = reinterpret_cast<const f32x4*>(V) + (size_t)d * 128;
        f32x4 v0 = Vr[lane];
        f32x4 v1 = Vr[64 + lane];
        float acc = s0.x * v0.x + s0.y * v0.y + s0.z * v0.z + s0.w * v0.w
                  + s1.x * v1.x + s1.y * v1.y + s1.z * v1.z + s1.w * v1.w;
#pragma unroll
        for (int m = 32; m > 0; m >>= 1) acc += __shfl_xor(acc, m);
        if (lane == 0) phi[(size_t)n * EE + h * DD + d] = acc;
    }
}

template<int K, int F, int NG, int FPW, int MODE>
__global__ __launch_bounds__(256) void k_gemm(const float* __restrict__ A,
                                              const float* __restrict__ W,
                                              const float* __restrict__ bias,
                                              const float* __restrict__ res,
                                              float* __restrict__ out) {
    constexpr int V4 = K / 256;
    int wid  = (blockIdx.x * 256 + threadIdx.x) >> 6;
    int lane = threadIdx.x & 63;
    constexpr int NGROUPS = NN / NG;
    int ng = wid % NGROUPS;
    int fc = wid / NGROUPS;
    int n0 = ng * NG;
    int f0 = fc * FPW;

    float4 a4[NG][V4];
#pragma unroll
    for (int g = 0; g < NG; ++g)
#pragma unroll
        for (int k = 0; k < V4; ++k)
            a4[g][k] = reinterpret_cast<const float4*>(
                A + (size_t)(n0 + g) * K)[k * 64 + lane];

#pragma unroll
    for (int fi = 0; fi < FPW; ++fi) {
        int f = f0 + fi;
        float4 w4[V4];
#pragma unroll
        for (int k = 0; k < V4; ++k)
            w4[k] = reinterpret_cast<const float4*>(
                W + (size_t)f * K)[k * 64 + lane];
        float acc[NG];
#pragma unroll
        for (int g = 0; g < NG; ++g) {
            float s = 0.f;
#pragma unroll
            for (int k = 0; k < V4; ++k) {
                s += a4[g][k].x * w4[k].x + a4[g][k].y * w4[k].y
                   + a4[g][k].z * w4[k].z + a4[g][k].w * w4[k].w;
            }
#pragma unroll
            for (int m = 32; m > 0; m >>= 1) s += __shfl_xor(s, m);
            acc[g] = s;
        }
        if (lane == 0) {
            float bv = (MODE == 0) ? 0.f : bias[f];
#pragma unroll
            for (int g = 0; g < NG; ++g) {
                float v = acc[g] + bv;
                if (MODE == 1) v = fmaxf(v, 0.f);
                if (MODE == 2) v += res[(size_t)(n0 + g) * F + f];
                out[(size_t)(n0 + g) * F + f] = v;
            }
        }
    }
}

__global__ void k_ln(const float* __restrict__ x, const float* __restrict__ gamma,
                     const float* __restrict__ beta, float* __restrict__ out) {
    __shared__ float wred[4];
    int n = blockIdx.x;
    int tid = threadIdx.x;
    float a = x[(size_t)n * EE + tid];
    float b = x[(size_t)n * EE + 256 + tid];
    float s = a + b;
#pragma unroll
    for (int off = 32; off > 0; off >>= 1) s += __shfl_down(s, off);
    int wid = tid >> 6;
    if ((tid & 63) == 0) wred[wid] = s;
    __syncthreads();
    if (tid == 0) wred[0] = (wred[0] + wred[1] + wred[2] + wred[3]) * (1.0f / EE);
    __syncthreads();
    float mu = wred[0];
    float da = a - mu, db = b - mu;
    float q = da * da + db * db;
#pragma unroll
    for (int off = 32; off > 0; off >>= 1) q += __shfl_down(q, off);
    __syncthreads();
    if ((tid & 63) == 0) wred[wid] = q;
    __syncthreads();
    if (tid == 0) wred[0] = (wred[0] + wred[1] + wred[2] + wred[3]) * (1.0f / EE);
    __syncthreads();
    float var = wred[0];
    float rstd = rsqrtf(var + 1e-5f);
    out[(size_t)n * EE + tid]       = da * rstd * gamma[tid] + beta[tid];
    out[(size_t)n * EE + 256 + tid] = db * rstd * gamma[tid + 256] + beta[tid + 256];
}

// ===========================================================================
extern "C" void kernel_launch(void* const* d_in, const int* in_sizes, int n_in,
                              void* d_out, int out_size, void* d_ws, size_t ws_size,
                              hipStream_t stream) {
    const float* Cp    = (const float*)d_in[0];
    const float* W1    = (const float*)d_in[1];
    // d_in[2] = W2: unused — softmax over a size-1 axis is identically 1.
    const float* W3    = (const float*)d_in[3];
    const float* Wf1   = (const float*)d_in[4];
    const float* bf1   = (const float*)d_in[5];
    const float* Wf2   = (const float*)d_in[6];
    const float* bf2   = (const float*)d_in[7];
    const float* gamma = (const float*)d_in[8];
    const float* beta  = (const float*)d_in[9];
    float* out = (float*)d_out;
    float* ws  = (float*)d_ws;

    // Zero the barrier counters (graph-legal async memset, deterministic).
    hipMemsetAsync((char*)d_ws + (size_t)CNT_OFF * 4, 0, 8 * sizeof(unsigned),
                   stream);

    void* args[] = {
        (void*)&Cp, (void*)&W1, (void*)&W3, (void*)&Wf1, (void*)&bf1,
        (void*)&Wf2, (void*)&bf2, (void*)&gamma, (void*)&beta,
        (void*)&out, (void*)&ws,
    };
    hipError_t err = hipLaunchCooperativeKernel((void*)k_mega, dim3(GRIDN),
                                                dim3(256), args, 0, stream);
    if (err == hipSuccess) return;

    // Fallback: verified six-kernel pipeline (R7, 78.3 us).
    float* P   = ws;
    float* V   = P + (size_t)CC * NN * HH * EE;
    float* phi = V + (size_t)DD * EE;
    float* w3  = phi + (size_t)NN * EE;
    float* h1  = w3 + (size_t)NN * EE;
    float* x   = h1 + (size_t)NN * FF;

    k_prep<<<2048 + 32, 128, 0, stream>>>(Cp, W1, P, V);
    k_phi<<<NN * HH, 256, 0, stream>>>(P, V, phi);
    k_gemm<EE, EE, 8, 2, 0><<<256, 256, 0, stream>>>(phi, W3, nullptr, nullptr, w3);
    k_gemm<EE, FF, 8, 2, 1><<<1024, 256, 0, stream>>>(w3, Wf1, bf1, nullptr, h1);
    k_gemm<FF, EE, 4, 1, 2><<<1024, 256, 0, stream>>>(h1, Wf2, bf2, w3, x);
    k_ln<<<NN, 256, 0, stream>>>(x, gamma, beta, out);
}

// Round 10
// 406.559 us; speedup vs baseline: 2.4303x; 2.4303x over previous
//
#include <hip/hip_runtime.h>
#include <hip/hip_bf16.h>

#define NN 32
#define LL 4096
#define EE 512
#define HH 8
#define DD 64
#define FF 2048
#define CC 8            // row chunks per head-block (512 rows / 64)

typedef float f32x4 __attribute__((ext_vector_type(4)));

// ---------------------------------------------------------------------------
// K1 (R2/R7-proven): blocks 0..2047: P[c][n][h][e] = 64-row partial sums of
// Cp; blocks 2048..2079: V[d][e] = sum_{j<8} W1[j*64+d][e]
__global__ void k_prep(const float* __restrict__ Cp, const float* __restrict__ W1,
                       float* __restrict__ P, float* __restrict__ V) {
    int bid = blockIdx.x;
    int tid = threadIdx.x;                 // 0..127
    if (bid < 2048) {
        int c = bid & 7;
        int h = (bid >> 3) & 7;
        int n = bid >> 6;
        const float4* base = reinterpret_cast<const float4*>(
            Cp + ((size_t)n * LL + (size_t)h * 512 + (size_t)c * 64) * EE) + tid;
        float ax = 0.f, ay = 0.f, az = 0.f, aw = 0.f;
#pragma unroll 8
        for (int r = 0; r < 64; ++r) {
            float4 v = base[(size_t)r * (EE / 4)];
            ax += v.x; ay += v.y; az += v.z; aw += v.w;
        }
        float4 o; o.x = ax; o.y = ay; o.z = az; o.w = aw;
        reinterpret_cast<float4*>(P + (((size_t)c * NN + n) * HH + h) * EE)[tid] = o;
    } else {
        int gid2 = (bid - 2048) * 128 + tid;     // 0..4095, 2 float4 outputs each
#pragma unroll
        for (int rep = 0; rep < 2; ++rep) {
            int idx = gid2 + rep * 4096;         // 0..8191
            int d = idx >> 7;
            int e4 = idx & 127;
            float ax = 0.f, ay = 0.f, az = 0.f, aw = 0.f;
#pragma unroll
            for (int j = 0; j < 8; ++j) {
                float4 v = reinterpret_cast<const float4*>(
                    W1 + (size_t)(j * 64 + d) * EE)[e4];
                ax += v.x; ay += v.y; az += v.z; aw += v.w;
            }
            float4 o; o.x = ax; o.y = ay; o.z = az; o.w = aw;
            reinterpret_cast<float4*>(V + (size_t)d * EE)[e4] = o;
        }
    }
}

// ---------------------------------------------------------------------------
// K2: per-n fused phi + w3.  32 blocks (one per n) x 256 threads (4 waves).
//   stage 1: S[h][e] = sum_c P[c][n][h][e]        (coalesced, 16 KB LDS)
//   stage 2: ph[h*64+d] = dot(S[h][:], V[d][:])   (wave-per-output, LDS dest)
//   stage 3: w3[n][f]  = dot(ph[:], W3[f][:])     (wave-per-f, lanes split K)
__global__ __launch_bounds__(256) void k_phiw3(const float* __restrict__ P,
                                               const float* __restrict__ V,
                                               const float* __restrict__ W3,
                                               float* __restrict__ w3) {
    __shared__ float S[HH * EE];      // 16 KB
    __shared__ float ph[EE];          // 2 KB
    int n = blockIdx.x;
    int t = threadIdx.x;
    int w = t >> 6;
    int lane = t & 63;

    f32x4* S4 = reinterpret_cast<f32x4*>(S);
    const f32x4* P4 = reinterpret_cast<const f32x4*>(P);
#pragma unroll
    for (int rep = 0; rep < 4; ++rep) {
        int idx = rep * 256 + t;      // 0..1023 = h*128 + e4
        f32x4 a = P4[(size_t)(0 * NN + n) * 1024 + idx];
#pragma unroll
        for (int c = 1; c < CC; ++c) {
            f32x4 b = P4[(size_t)(c * NN + n) * 1024 + idx];
            a.x += b.x; a.y += b.y; a.z += b.z; a.w += b.w;
        }
        S4[idx] = a;
    }
    __syncthreads();

    // stage 2: wave w computes outputs o = w*128 .. w*128+127  (o = h*64+d)
    const f32x4* V4 = reinterpret_cast<const f32x4*>(V);
    for (int i = 0; i < 128; ++i) {
        int o = w * 128 + i;
        int h = o >> 6, d = o & 63;
        f32x4 s0 = S4[h * 128 + lane];
        f32x4 s1 = S4[h * 128 + 64 + lane];
        f32x4 v0 = V4[(size_t)d * 128 + lane];
        f32x4 v1 = V4[(size_t)d * 128 + 64 + lane];
        float acc = s0.x * v0.x + s0.y * v0.y + s0.z * v0.z + s0.w * v0.w
                  + s1.x * v1.x + s1.y * v1.y + s1.z * v1.z + s1.w * v1.w;
#pragma unroll
        for (int m = 32; m > 0; m >>= 1) acc += __shfl_xor(acc, m);
        if (lane == 0) ph[o] = acc;
    }
    __syncthreads();

    // stage 3: wave w computes f = w*128 .. +127
    const f32x4* PH4 = reinterpret_cast<const f32x4*>(ph);
    const f32x4* W34 = reinterpret_cast<const f32x4*>(W3);
    f32x4 p0 = PH4[lane];
    f32x4 p1 = PH4[64 + lane];
    for (int i = 0; i < 128; ++i) {
        int f = w * 128 + i;
        f32x4 w0 = W34[(size_t)f * 128 + lane];
        f32x4 w1 = W34[(size_t)f * 128 + 64 + lane];
        float acc = p0.x * w0.x + p0.y * w0.y + p0.z * w0.z + p0.w * w0.w
                  + p1.x * w1.x + p1.y * w1.y + p1.z * w1.z + p1.w * w1.w;
#pragma unroll
        for (int m = 32; m > 0; m >>= 1) acc += __shfl_xor(acc, m);
        if (lane == 0) w3[(size_t)n * EE + f] = acc;
    }
}

// ---------------------------------------------------------------------------
// K3 (R2-proven): h1 = relu(w3 @ Wf1^T + bf1)
template<int K, int F, int NG, int FPW, int MODE>
__global__ __launch_bounds__(256) void k_gemm(const float* __restrict__ A,
                                              const float* __restrict__ W,
                                              const float* __restrict__ bias,
                                              const float* __restrict__ res,
                                              float* __restrict__ out) {
    constexpr int V4 = K / 256;
    int wid  = (blockIdx.x * 256 + threadIdx.x) >> 6;
    int lane = threadIdx.x & 63;
    constexpr int NGROUPS = NN / NG;
    int ng = wid % NGROUPS;
    int fc = wid / NGROUPS;
    int n0 = ng * NG;
    int f0 = fc * FPW;

    float4 a4[NG][V4];
#pragma unroll
    for (int g = 0; g < NG; ++g)
#pragma unroll
        for (int k = 0; k < V4; ++k)
            a4[g][k] = reinterpret_cast<const float4*>(
                A + (size_t)(n0 + g) * K)[k * 64 + lane];

#pragma unroll
    for (int fi = 0; fi < FPW; ++fi) {
        int f = f0 + fi;
        float4 w4[V4];
#pragma unroll
        for (int k = 0; k < V4; ++k)
            w4[k] = reinterpret_cast<const float4*>(
                W + (size_t)f * K)[k * 64 + lane];
        float acc[NG];
#pragma unroll
        for (int g = 0; g < NG; ++g) {
            float s = 0.f;
#pragma unroll
            for (int k = 0; k < V4; ++k) {
                s += a4[g][k].x * w4[k].x + a4[g][k].y * w4[k].y
                   + a4[g][k].z * w4[k].z + a4[g][k].w * w4[k].w;
            }
#pragma unroll
            for (int m = 32; m > 0; m >>= 1) s += __shfl_xor(s, m);
            acc[g] = s;
        }
        if (lane == 0) {
            float bv = (MODE == 0) ? 0.f : bias[f];
#pragma unroll
            for (int g = 0; g < NG; ++g) {
                float v = acc[g] + bv;
                if (MODE == 1) v = fmaxf(v, 0.f);
                if (MODE == 2) v += res[(size_t)(n0 + g) * F + f];
                out[(size_t)(n0 + g) * F + f] = v;
            }
        }
    }
}

// ---------------------------------------------------------------------------
// K4: per-n fused ffn2 + residual + LayerNorm.  32 blocks x 256 threads.
//   stage 1: hbuf = h1[n][:2048] -> LDS (coalesced)
//   stage 2: wave-per-e: x[e] = dot(hbuf, Wf2[e][:]) + bf2[e] + w3[n][e]
//   stage 3: LayerNorm over x (LDS) -> out
__global__ __launch_bounds__(256) void k_ffn2ln(const float* __restrict__ h1,
                                                const float* __restrict__ Wf2,
                                                const float* __restrict__ bf2,
                                                const float* __restrict__ w3,
                                                const float* __restrict__ gamma,
                                                const float* __restrict__ beta,
                                                float* __restrict__ out) {
    __shared__ float hbuf[FF];        // 8 KB
    __shared__ float xbuf[EE];        // 2 KB
    __shared__ float wred[4];
    int n = blockIdx.x;
    int t = threadIdx.x;
    int w = t >> 6;
    int lane = t & 63;

    f32x4* HB4 = reinterpret_cast<f32x4*>(hbuf);
    const f32x4* H4 = reinterpret_cast<const f32x4*>(h1) + (size_t)n * 512;
#pragma unroll
    for (int rep = 0; rep < 2; ++rep)
        HB4[rep * 256 + t] = H4[rep * 256 + t];
    __syncthreads();

    f32x4 hb[8];
#pragma unroll
    for (int k = 0; k < 8; ++k) hb[k] = HB4[k * 64 + lane];

    const f32x4* WF4 = reinterpret_cast<const f32x4*>(Wf2);
    for (int i = 0; i < 128; ++i) {
        int e = w * 128 + i;
        const f32x4* Wr = WF4 + (size_t)e * 512;
        float acc = 0.f;
#pragma unroll
        for (int k = 0; k < 8; ++k) {
            f32x4 ww = Wr[k * 64 + lane];
            acc += hb[k].x * ww.x + hb[k].y * ww.y + hb[k].z * ww.z + hb[k].w * ww.w;
        }
#pragma unroll
        for (int m = 32; m > 0; m >>= 1) acc += __shfl_xor(acc, m);
        if (lane == 0) xbuf[e] = acc + bf2[e] + w3[(size_t)n * EE + e];
    }
    __syncthreads();

    // LayerNorm over xbuf[512]
    float a = xbuf[t];
    float b = xbuf[256 + t];
    float s = a + b;
#pragma unroll
    for (int off = 32; off > 0; off >>= 1) s += __shfl_down(s, off);
    if ((t & 63) == 0) wred[w] = s;
    __syncthreads();
    if (t == 0) wred[0] = (wred[0] + wred[1] + wred[2] + wred[3]) * (1.0f / EE);
    __syncthreads();
    float mu = wred[0];
    float da = a - mu, db = b - mu;
    float q = da * da + db * db;
#pragma unroll
    for (int off = 32; off > 0; off >>= 1) q += __shfl_down(q, off);
    __syncthreads();
    if ((t & 63) == 0) wred[w] = q;
    __syncthreads();
    if (t == 0) wred[0] = (wred[0] + wred[1] + wred[2] + wred[3]) * (1.0f / EE);
    __syncthreads();
    float var = wred[0];
    float rstd = rsqrtf(var + 1e-5f);
    out[(size_t)n * EE + t]       = da * rstd * gamma[t] + beta[t];
    out[(size_t)n * EE + 256 + t] = db * rstd * gamma[t + 256] + beta[t + 256];
}

// ---------------------------------------------------------------------------
extern "C" void kernel_launch(void* const* d_in, const int* in_sizes, int n_in,
                              void* d_out, int out_size, void* d_ws, size_t ws_size,
                              hipStream_t stream) {
    const float* Cp    = (const float*)d_in[0];
    const float* W1    = (const float*)d_in[1];
    // d_in[2] = W2: unused — softmax over a size-1 axis is identically 1.
    const float* W3    = (const float*)d_in[3];
    const float* Wf1   = (const float*)d_in[4];
    const float* bf1   = (const float*)d_in[5];
    const float* Wf2   = (const float*)d_in[6];
    const float* bf2   = (const float*)d_in[7];
    const float* gamma = (const float*)d_in[8];
    const float* beta  = (const float*)d_in[9];
    float* out = (float*)d_out;
    float* ws  = (float*)d_ws;

    float* P  = ws;                               // 8*32*8*512 = 1,048,576 floats
    float* V  = P + (size_t)CC * NN * HH * EE;    // 64*512
    float* w3 = V + (size_t)DD * EE;              // 32*512
    float* h1 = w3 + (size_t)NN * EE;             // 32*2048

    // K1: Cp row-block partial sums + W1 colsums
    k_prep<<<2048 + 32, 128, 0, stream>>>(Cp, W1, P, V);
    // K2: per-n fused phi + w3
    k_phiw3<<<NN, 256, 0, stream>>>(P, V, W3, w3);
    // K3: h1 = relu(w3 @ Wf1^T + bf1)
    k_gemm<EE, FF, 8, 2, 1><<<1024, 256, 0, stream>>>(w3, Wf1, bf1, nullptr, h1);
    // K4: per-n fused ffn2 + residual + LayerNorm
    k_ffn2ln<<<NN, 256, 0, stream>>>(h1, Wf2, bf2, w3, gamma, beta, out);
}